// Round 2
// baseline (314.013 us; speedup 1.0000x reference)
//
#include <hip/hip_runtime.h>
#include <math.h>

#define HH 512
#define WW 512
#define PHH 16
#define PWW 16
#define QQ 3
#define NHH 32
#define NWW 32
#define PP 1024
#define BB 64

// Twiddles: TW[j] = exp(-2*pi*i*j/16), j = 0..7
__device__ __constant__ float TWC[8] = {
    1.0f,  0.92387953251f,  0.70710678119f,  0.38268343236f,
    0.0f, -0.38268343236f, -0.70710678119f, -0.92387953251f};
__device__ __constant__ float TWS[8] = {
    0.0f, -0.38268343236f, -0.70710678119f, -0.92387953251f,
   -1.0f, -0.92387953251f, -0.70710678119f, -0.38268343236f};

// Fully-unrolled in-register 16-point complex FFT (radix-2 DIT).
// SGN=+1: forward (exp(-i)); SGN=-1: unscaled inverse (exp(+i)).
template <int SGN>
__device__ __forceinline__ void fft16(float* re, float* im) {
#define SWAP_(a, b)                              \
  { float t = re[a]; re[a] = re[b]; re[b] = t;   \
    t = im[a]; im[a] = im[b]; im[b] = t; }
  SWAP_(1, 8) SWAP_(2, 4) SWAP_(3, 12) SWAP_(5, 10) SWAP_(7, 14) SWAP_(11, 13)
#undef SWAP_
#pragma unroll
  for (int len = 2; len <= 16; len <<= 1) {
    const int half = len >> 1;
    const int tstep = 16 / len;
#pragma unroll
    for (int i = 0; i < 16; i += len) {
#pragma unroll
      for (int j = 0; j < half; ++j) {
        const float wr = TWC[j * tstep];
        const float wi = (SGN > 0) ? TWS[j * tstep] : -TWS[j * tstep];
        const int a = i + j;
        const int c = i + j + half;
        const float tr = re[c] * wr - im[c] * wi;
        const float ti = re[c] * wi + im[c] * wr;
        re[c] = re[a] - tr;
        im[c] = im[a] - ti;
        re[a] = re[a] + tr;
        im[a] = im[a] + ti;
      }
    }
  }
}

// In-register 16x16 transpose across a 16-lane group via butterfly
// exchanges. Composition of 4 stages (s=1,2,4,8), each swapping element
// (l,j) <-> (l^s, j^s) for (l&s)!=(j&s), yields (l,j)->(j,l) exactly.
// r = lane index within the 16-lane group; masks <16 never cross groups
// within the 64-lane wave.
__device__ __forceinline__ void transpose16(float* re, float* im, int r) {
#pragma unroll
  for (int s = 1; s <= 8; s <<= 1) {
    const bool hi = (r & s) != 0;
#pragma unroll
    for (int j0 = 0; j0 < 16; ++j0) {
      if ((j0 & s) == 0) {
        const int j1 = j0 | s;
        float sr = hi ? re[j0] : re[j1];
        float si = hi ? im[j0] : im[j1];
        sr = __shfl_xor(sr, s, 64);
        si = __shfl_xor(si, s, 64);
        if (hi) {
          re[j0] = sr;
          im[j0] = si;
        } else {
          re[j1] = sr;
          im[j1] = si;
        }
      }
    }
  }
}

// Block: 256 threads = 16 groups x 16 lanes.
// Block handles one patch p and 16 batch indices; group g -> batch b0+g,
// lane r within group -> row r of the 16x16 patch.
__global__ __launch_bounds__(256) void psm_kernel(
    const float* __restrict__ x, const float* __restrict__ logits,
    const float* __restrict__ mu, const float* __restrict__ sigma,
    const float* __restrict__ bias, float* __restrict__ out) {
  __shared__ float S_lds[256];

  const int tid = threadIdx.x;
  const int p = blockIdx.x >> 2;
  const int b0 = (blockIdx.x & 3) << 4;
  const int g = tid >> 4;
  const int r = tid & 15;
  const int b = b0 + g;
  const int nh = p >> 5;
  const int nw = p & 31;

  // ---- issue the x loads early so they overlap the S computation ----
  const size_t rowoff =
      (size_t)b * (HH * WW) + (size_t)(nh * PHH + r) * WW + (size_t)(nw * PWW);
  const float* xrow = x + rowoff;
  float4 xv0 = ((const float4*)xrow)[0];
  float4 xv1 = ((const float4*)xrow)[1];
  float4 xv2 = ((const float4*)xrow)[2];
  float4 xv3 = ((const float4*)xrow)[3];

  // ---- spectral filter S for this patch into LDS (one bin/thread) ----
  {
    const int fy_i = tid >> 4;
    const int fx_i = tid & 15;
    const float fy = (float)(fy_i < 8 ? fy_i : fy_i - 16) * (1.0f / 16.0f);
    const float fx = (float)(fx_i < 8 ? fx_i : fx_i - 16) * (1.0f / 16.0f);
    const float l0 = logits[p * QQ + 0];
    const float l1 = logits[p * QQ + 1];
    const float l2 = logits[p * QQ + 2];
    const float lm = fmaxf(l0, fmaxf(l1, l2));
    const float e0 = __expf(l0 - lm);
    const float e1 = __expf(l1 - lm);
    const float e2 = __expf(l2 - lm);
    const float inv = 1.0f / (e0 + e1 + e2);
    const float wq[3] = {e0 * inv, e1 * inv, e2 * inv};
    float s = 0.0f;
#pragma unroll
    for (int q = 0; q < QQ; ++q) {
      const float muy = mu[(p * QQ + q) * 2 + 0];
      const float mux = mu[(p * QQ + q) * 2 + 1];
      const float isy = 1.0f / sigma[(p * QQ + q) * 2 + 0];
      const float isx = 1.0f / sigma[(p * QQ + q) * 2 + 1];
      const float dy1 = (fy - muy) * isy;
      const float dx1 = (fx - mux) * isx;
      const float dy2 = (fy + muy) * isy;
      const float dx2 = (fx + mux) * isx;
      const float g1 = __expf(-0.5f * (dy1 * dy1 + dx1 * dx1));
      const float g2 = __expf(-0.5f * (dy2 * dy2 + dx2 * dx2));
      s += wq[q] * (g1 + g2);
    }
    // fold jitter and the ifft2 1/256 normalization into S
    S_lds[tid] = (s + 1e-6f) * (1.0f / 256.0f);
  }
  __syncthreads();  // the ONLY barrier: S ready before the multiply below

  // ---- forward row FFT (im=0 folds away in the unrolled code) ----
  float re[16], im[16];
  re[0] = xv0.x;  re[1] = xv0.y;  re[2] = xv0.z;  re[3] = xv0.w;
  re[4] = xv1.x;  re[5] = xv1.y;  re[6] = xv1.z;  re[7] = xv1.w;
  re[8] = xv2.x;  re[9] = xv2.y;  re[10] = xv2.z; re[11] = xv2.w;
  re[12] = xv3.x; re[13] = xv3.y; re[14] = xv3.z; re[15] = xv3.w;
#pragma unroll
  for (int c = 0; c < 16; ++c) im[c] = 0.0f;
  fft16<1>(re, im);

  // ---- transpose, column FFT, S multiply, inverse column FFT ----
  transpose16(re, im, r);
  fft16<1>(re, im);
#pragma unroll
  for (int k = 0; k < 16; ++k) {
    const float s = S_lds[k * 16 + r];
    re[k] *= s;
    im[k] *= s;
  }
  fft16<-1>(re, im);

  // ---- transpose back, inverse row FFT (im output is dead code) ----
  transpose16(re, im, r);
  fft16<-1>(re, im);

  // ---- real part + bias, vector store ----
  const float* brow = bias + (size_t)p * 256 + (size_t)r * 16;
  float* orow = out + rowoff;
#pragma unroll
  for (int c4 = 0; c4 < 4; ++c4) {
    const float4 bv = ((const float4*)brow)[c4];
    float4 o;
    o.x = re[c4 * 4 + 0] + bv.x;
    o.y = re[c4 * 4 + 1] + bv.y;
    o.z = re[c4 * 4 + 2] + bv.z;
    o.w = re[c4 * 4 + 3] + bv.w;
    ((float4*)orow)[c4] = o;
  }
}

extern "C" void kernel_launch(void* const* d_in, const int* in_sizes, int n_in,
                              void* d_out, int out_size, void* d_ws,
                              size_t ws_size, hipStream_t stream) {
  (void)in_sizes;
  (void)n_in;
  (void)out_size;
  (void)d_ws;
  (void)ws_size;
  const float* x = (const float*)d_in[0];
  const float* logits = (const float*)d_in[1];
  const float* mu = (const float*)d_in[2];
  const float* sigma = (const float*)d_in[3];
  const float* bias = (const float*)d_in[4];
  float* out = (float*)d_out;

  // 1024 patches x 4 batch-chunks of 16
  psm_kernel<<<dim3(PP * 4), dim3(256), 0, stream>>>(x, logits, mu, sigma,
                                                     bias, out);
}

// Round 3
// 151.931 us; speedup vs baseline: 2.0668x; 2.0668x over previous
//
#include <hip/hip_runtime.h>
#include <math.h>

#define HH 512
#define WW 512
#define PHH 16
#define PWW 16
#define QQ 3
#define NHH 32
#define NWW 32
#define PP 1024
#define BB 64

// Twiddles: TW[j] = exp(-2*pi*i*j/16), j = 0..7
__device__ __constant__ float TWC[8] = {
    1.0f,  0.92387953251f,  0.70710678119f,  0.38268343236f,
    0.0f, -0.38268343236f, -0.70710678119f, -0.92387953251f};
__device__ __constant__ float TWS[8] = {
    0.0f, -0.38268343236f, -0.70710678119f, -0.92387953251f,
   -1.0f, -0.92387953251f, -0.70710678119f, -0.38268343236f};

// Fully-unrolled in-register 16-point complex FFT (radix-2 DIT).
// SGN=+1: forward (exp(-i)); SGN=-1: unscaled inverse (exp(+i)).
template <int SGN>
__device__ __forceinline__ void fft16(float* re, float* im) {
#define SWAP_(a, b)                              \
  { float t = re[a]; re[a] = re[b]; re[b] = t;   \
    t = im[a]; im[a] = im[b]; im[b] = t; }
  SWAP_(1, 8) SWAP_(2, 4) SWAP_(3, 12) SWAP_(5, 10) SWAP_(7, 14) SWAP_(11, 13)
#undef SWAP_
#pragma unroll
  for (int len = 2; len <= 16; len <<= 1) {
    const int half = len >> 1;
    const int tstep = 16 / len;
#pragma unroll
    for (int i = 0; i < 16; i += len) {
#pragma unroll
      for (int j = 0; j < half; ++j) {
        const float wr = TWC[j * tstep];
        const float wi = (SGN > 0) ? TWS[j * tstep] : -TWS[j * tstep];
        const int a = i + j;
        const int c = i + j + half;
        const float tr = re[c] * wr - im[c] * wi;
        const float ti = re[c] * wi + im[c] * wr;
        re[c] = re[a] - tr;
        im[c] = im[a] - ti;
        re[a] = re[a] + tr;
        im[a] = im[a] + ti;
      }
    }
  }
}

// Block: 256 threads = 16 groups x 16 lanes. Block handles one patch p and
// 32 batch indices: group g packs batches (b0+2g, b0+2g+1) as one complex
// image z = x_b1 + i*x_b2. Since S is real and index-even (S[k]=S[(16-k)%16]),
// ifft2(fft2(x)*S) is exactly real for real x, so by real-linearity
// Re(result)=y_b1 and Im(result)=y_b2. One complex pipeline serves 2 batches.
__global__ __launch_bounds__(256) void psm_kernel(
    const float* __restrict__ x, const float* __restrict__ logits,
    const float* __restrict__ mu, const float* __restrict__ sigma,
    const float* __restrict__ bias, float* __restrict__ out) {
  __shared__ float S_lds[256];
  __shared__ float t_re[16 * 272];  // 16 groups, 16x16 tile, stride 17
  __shared__ float t_im[16 * 272];

  const int tid = threadIdx.x;
  const int p = blockIdx.x >> 1;
  const int b0 = (blockIdx.x & 1) << 5;  // 0 or 32
  const int g = tid >> 4;
  const int r = tid & 15;
  const int b1 = b0 + 2 * g;
  const int nh = p >> 5;
  const int nw = p & 31;

  // ---- issue the x loads early so they overlap the S computation ----
  const size_t rowbase =
      (size_t)(nh * PHH + r) * WW + (size_t)(nw * PWW);
  const float* x1 = x + (size_t)b1 * (HH * WW) + rowbase;
  const float* x2 = x1 + (size_t)(HH * WW);
  const float4 a0 = ((const float4*)x1)[0];
  const float4 a1 = ((const float4*)x1)[1];
  const float4 a2 = ((const float4*)x1)[2];
  const float4 a3 = ((const float4*)x1)[3];
  const float4 c0 = ((const float4*)x2)[0];
  const float4 c1 = ((const float4*)x2)[1];
  const float4 c2 = ((const float4*)x2)[2];
  const float4 c3 = ((const float4*)x2)[3];

  // ---- spectral filter S for this patch into LDS (one bin/thread) ----
  {
    const int fy_i = tid >> 4;
    const int fx_i = tid & 15;
    const float fy = (float)(fy_i < 8 ? fy_i : fy_i - 16) * (1.0f / 16.0f);
    const float fx = (float)(fx_i < 8 ? fx_i : fx_i - 16) * (1.0f / 16.0f);
    const float l0 = logits[p * QQ + 0];
    const float l1 = logits[p * QQ + 1];
    const float l2 = logits[p * QQ + 2];
    const float lm = fmaxf(l0, fmaxf(l1, l2));
    const float e0 = __expf(l0 - lm);
    const float e1 = __expf(l1 - lm);
    const float e2 = __expf(l2 - lm);
    const float inv = 1.0f / (e0 + e1 + e2);
    const float wq[3] = {e0 * inv, e1 * inv, e2 * inv};
    float s = 0.0f;
#pragma unroll
    for (int q = 0; q < QQ; ++q) {
      const float muy = mu[(p * QQ + q) * 2 + 0];
      const float mux = mu[(p * QQ + q) * 2 + 1];
      const float isy = 1.0f / sigma[(p * QQ + q) * 2 + 0];
      const float isx = 1.0f / sigma[(p * QQ + q) * 2 + 1];
      const float dy1 = (fy - muy) * isy;
      const float dx1 = (fx - mux) * isx;
      const float dy2 = (fy + muy) * isy;
      const float dx2 = (fx + mux) * isx;
      const float g1 = __expf(-0.5f * (dy1 * dy1 + dx1 * dx1));
      const float g2 = __expf(-0.5f * (dy2 * dy2 + dx2 * dx2));
      s += wq[q] * (g1 + g2);
    }
    // fold jitter and the ifft2 1/256 normalization into S
    S_lds[tid] = (s + 1e-6f) * (1.0f / 256.0f);
  }
  // NOTE: no barrier here — the transpose barrier below also publishes S_lds.

  // ---- forward row FFT on packed complex rows z = x_b1 + i*x_b2 ----
  float re[16], im[16];
  re[0] = a0.x;  re[1] = a0.y;  re[2] = a0.z;  re[3] = a0.w;
  re[4] = a1.x;  re[5] = a1.y;  re[6] = a1.z;  re[7] = a1.w;
  re[8] = a2.x;  re[9] = a2.y;  re[10] = a2.z; re[11] = a2.w;
  re[12] = a3.x; re[13] = a3.y; re[14] = a3.z; re[15] = a3.w;
  im[0] = c0.x;  im[1] = c0.y;  im[2] = c0.z;  im[3] = c0.w;
  im[4] = c1.x;  im[5] = c1.y;  im[6] = c1.z;  im[7] = c1.w;
  im[8] = c2.x;  im[9] = c2.y;  im[10] = c2.z; im[11] = c2.w;
  im[12] = c3.x; im[13] = c3.y; im[14] = c3.z; im[15] = c3.w;
  fft16<1>(re, im);

  // ---- transpose #1 via LDS (row write, column read) ----
  float* mre = &t_re[g * 272];
  float* mim = &t_im[g * 272];
#pragma unroll
  for (int c = 0; c < 16; ++c) {
    mre[r * 17 + c] = re[c];
    mim[r * 17 + c] = im[c];
  }
  __syncthreads();  // barrier 1: T1 data + S_lds published
#pragma unroll
  for (int k = 0; k < 16; ++k) {
    re[k] = mre[k * 17 + r];
    im[k] = mim[k * 17 + r];
  }

  // ---- column FFT, multiply by S, inverse column FFT ----
  fft16<1>(re, im);
#pragma unroll
  for (int k = 0; k < 16; ++k) {
    const float s = S_lds[k * 16 + r];
    re[k] *= s;
    im[k] *= s;
  }
  fft16<-1>(re, im);

  // ---- transpose #2 (column write, row read) ----
  __syncthreads();  // barrier 2: WAR — everyone done reading T1 buffers
#pragma unroll
  for (int k = 0; k < 16; ++k) {
    mre[k * 17 + r] = re[k];
    mim[k * 17 + r] = im[k];
  }
  __syncthreads();  // barrier 3: T2 data published
#pragma unroll
  for (int c = 0; c < 16; ++c) {
    re[c] = mre[r * 17 + c];
    im[c] = mim[r * 17 + c];
  }

  // ---- inverse row FFT: re -> y_b1, im -> y_b2 ----
  fft16<-1>(re, im);

  // ---- bias (shared by both batches) + vector stores ----
  const float* brow = bias + (size_t)p * 256 + (size_t)r * 16;
  float* o1 = out + (size_t)b1 * (HH * WW) + rowbase;
  float* o2 = o1 + (size_t)(HH * WW);
#pragma unroll
  for (int c4 = 0; c4 < 4; ++c4) {
    const float4 bv = ((const float4*)brow)[c4];
    float4 u, v;
    u.x = re[c4 * 4 + 0] + bv.x;
    u.y = re[c4 * 4 + 1] + bv.y;
    u.z = re[c4 * 4 + 2] + bv.z;
    u.w = re[c4 * 4 + 3] + bv.w;
    v.x = im[c4 * 4 + 0] + bv.x;
    v.y = im[c4 * 4 + 1] + bv.y;
    v.z = im[c4 * 4 + 2] + bv.z;
    v.w = im[c4 * 4 + 3] + bv.w;
    ((float4*)o1)[c4] = u;
    ((float4*)o2)[c4] = v;
  }
}

extern "C" void kernel_launch(void* const* d_in, const int* in_sizes, int n_in,
                              void* d_out, int out_size, void* d_ws,
                              size_t ws_size, hipStream_t stream) {
  (void)in_sizes;
  (void)n_in;
  (void)out_size;
  (void)d_ws;
  (void)ws_size;
  const float* x = (const float*)d_in[0];
  const float* logits = (const float*)d_in[1];
  const float* mu = (const float*)d_in[2];
  const float* sigma = (const float*)d_in[3];
  const float* bias = (const float*)d_in[4];
  float* out = (float*)d_out;

  // 1024 patches x 2 batch-chunks of 32 (16 groups x 2 packed batches)
  psm_kernel<<<dim3(PP * 2), dim3(256), 0, stream>>>(x, logits, mu, sigma,
                                                     bias, out);
}